// Round 3
// baseline (583.546 us; speedup 1.0000x reference)
//
#include <hip/hip_runtime.h>
#include <hip/hip_bf16.h>
#include <math.h>

#define N_NODES 100000
#define N_EDGES 1600000
#define IN_DIM 64
#define OUT_DIM 64
#define HEADS 4
#define CH 16          // per-head channels
#define EDGE_DIM 16
#define NEG_SLOPE 0.2f
#define LN_EPS 1e-5f
#define NBLK 391       // ceil(N_NODES/256)
#define CHUNK 32       // CSR positions per wave in k_attn_agg

typedef unsigned short u16;
typedef unsigned int u32;
typedef unsigned long long u64;
typedef __attribute__((ext_vector_type(8))) short bf16x8;
typedef __attribute__((ext_vector_type(4))) float f32x4;

__device__ __forceinline__ float bf2f(u16 v) {
    return __uint_as_float(((u32)v) << 16);
}
__device__ __forceinline__ u16 f2bf(float f) {
    u32 u = __float_as_uint(f);
    u32 r = (u + 0x7FFFu + ((u >> 16) & 1u)) >> 16;   // RNE
    return (u16)r;
}
// load 16 consecutive bf16 (32B, 16B-aligned) -> 16 floats
__device__ __forceinline__ void load16bf(const u16* p, float* out) {
    const uint4* q = (const uint4*)p;
    uint4 a = q[0], b = q[1];
    u32 w[8] = {a.x, a.y, a.z, a.w, b.x, b.y, b.z, b.w};
#pragma unroll
    for (int i = 0; i < 8; ++i) {
        out[2*i]   = __uint_as_float(w[i] << 16);
        out[2*i+1] = __uint_as_float(w[i] & 0xFFFF0000u);
    }
}
__device__ __forceinline__ void load16f(const void* base, long i, bool f32in, float* out) {
    if (f32in) {
        const float4* q = (const float4*)((const float*)base + i);
        float4 v0 = q[0], v1 = q[1], v2 = q[2], v3 = q[3];
        out[0]=v0.x; out[1]=v0.y; out[2]=v0.z; out[3]=v0.w;
        out[4]=v1.x; out[5]=v1.y; out[6]=v1.z; out[7]=v1.w;
        out[8]=v2.x; out[9]=v2.y; out[10]=v2.z; out[11]=v2.w;
        out[12]=v3.x; out[13]=v3.y; out[14]=v3.z; out[15]=v3.w;
    } else {
        load16bf((const u16*)base + i, out);
    }
}
__device__ __forceinline__ float ldf(const void* base, int i, bool f32in) {
    return f32in ? ((const float*)base)[i] : bf2f(((const u16*)base)[i]);
}

// VALU-pipe 16-lane (DPP row) rotate-add reduction step
#define DPP_ROR_ADD(v, N) do { \
    int _d = __builtin_amdgcn_update_dpp(0, __float_as_int(v), 0x120 + (N), 0xF, 0xF, true); \
    (v) += __int_as_float(_d); } while (0)

// ---------------- pass 0: sniff dtypes (block 0) + zero cur & gsum (blocks 1..) ----------------
// bit0: 1 = float tensors stored f32, 0 = bf16; bit1: 1 = edge_index int64
__global__ void k_sniff_zero(const u32* __restrict__ xw, const int* __restrict__ eiw,
                             int* __restrict__ flags, int4* __restrict__ cur4,
                             float4* __restrict__ gsum4) {
    if (blockIdx.x != 0) {
        const int i = (blockIdx.x - 1) * 256 + threadIdx.x;
        if (i < N_NODES / 4) cur4[i] = make_int4(0, 0, 0, 0);
        else if (i < N_NODES / 2) gsum4[i - N_NODES / 4] = make_float4(0.f, 0.f, 0.f, 0.f);
        return;
    }
    __shared__ int s_f32, s_not64;
    const int t = threadIdx.x;
    if (t == 0) { s_f32 = 0; s_not64 = 0; }
    __syncthreads();
    if (t < 64) {
        u32 w = xw[t];
        for (int h = 0; h < 2; ++h) {
            u32 bits = h ? (w & 0xFFFF0000u) : (w << 16);
            float v = __uint_as_float(bits);
            float a = fabsf(v);
            bool sane = (a == 0.0f) || (a >= 1e-30f && a <= 1000.0f);
            if (!sane || v != v) atomicOr(&s_f32, 1);
        }
    } else if (t < 96) {
        if (eiw[2 * (t - 64) + 1] != 0) atomicOr(&s_not64, 1);
    }
    __syncthreads();
    if (t == 0) flags[0] = s_f32 | ((s_not64 ? 0 : 1) << 1);
}

// ---------------- pass 1: MFMA node transform: [xl|xr] = x @ [Wl|Wr] + [bl|br] ----------------
// block = 256 thr = 4 waves; block handles 64 nodes; wave w covers output cols [w*32, w*32+32)
__global__ __launch_bounds__(256) void k_transform(
    const void* __restrict__ x,
    const void* __restrict__ Wl, const void* __restrict__ bl,
    const void* __restrict__ Wr, const void* __restrict__ br,
    u16* __restrict__ xl, u16* __restrict__ xr,
    const int* __restrict__ flags)
{
    const bool f32in = (flags[0] & 1) != 0;
    const int lane = threadIdx.x & 63;
    const int w = threadIdx.x >> 6;
    const int m0 = blockIdx.x * 64;
    const int col = lane & 15;
    const int quad = lane >> 4;

    // B-fragments (grid-invariant): B[k][n] over cat(Wl,Wr); A/B layout: idx k = quad*8+j
    bf16x8 bfrag[2][2];   // [n-tile][k-chunk]
    float bias[2];
#pragma unroll
    for (int nt = 0; nt < 2; ++nt) {
        const int ng = w * 32 + nt * 16 + col;
        const void* W  = (ng < 64) ? Wl : Wr;
        const void* bi = (ng < 64) ? bl : br;
        const int c = ng & 63;
        bias[nt] = ldf(bi, c, f32in);
#pragma unroll
        for (int kf = 0; kf < 2; ++kf)
#pragma unroll
            for (int j = 0; j < 8; ++j) {
                const int k = kf * 32 + quad * 8 + j;
                bfrag[nt][kf][j] = (short)f2bf(ldf(W, k * 64 + c, f32in));
            }
    }

#pragma unroll
    for (int mt = 0; mt < 4; ++mt) {
        const int mrow = m0 + mt * 16 + col;
        const int m = (mrow < N_NODES) ? mrow : (N_NODES - 1);   // clamp: no OOB read
        bf16x8 afrag[2];
#pragma unroll
        for (int kf = 0; kf < 2; ++kf) {
            const int kb = kf * 32 + quad * 8;
            if (f32in) {
                const float* xp = (const float*)x + (size_t)m * 64 + kb;
#pragma unroll
                for (int j = 0; j < 8; ++j) afrag[kf][j] = (short)f2bf(xp[j]);
            } else {
                afrag[kf] = *(const bf16x8*)((const u16*)x + (size_t)m * 64 + kb);
            }
        }
#pragma unroll
        for (int nt = 0; nt < 2; ++nt) {
            f32x4 c = {bias[nt], bias[nt], bias[nt], bias[nt]};
            c = __builtin_amdgcn_mfma_f32_16x16x32_bf16(afrag[0], bfrag[nt][0], c, 0, 0, 0);
            c = __builtin_amdgcn_mfma_f32_16x16x32_bf16(afrag[1], bfrag[nt][1], c, 0, 0, 0);
            const int ng = w * 32 + nt * 16 + col;
            u16* dst = (ng < 64) ? xl : xr;
            const int cc = ng & 63;
#pragma unroll
            for (int r = 0; r < 4; ++r) {
                const int node = m0 + mt * 16 + quad * 4 + r;   // C: row=quad*4+r, col=lane&15
                if (node < N_NODES) dst[(size_t)node * 64 + cc] = f2bf(c[r]);
            }
        }
    }
}

// ---------------- pass 2a: degree histogram + zero accum region + edge-gate MLP ----------------
// grid 6250 x 256 == E exactly; also grid-strides the f32 accumulator zeroing.
// Gate MLP moved here from the scatter pass: its edge_attr read is fully
// coalesced (e == gid), its 740 VALU ops/thread overlap the atomics/zeroing,
// and the scatter pass is left with only its short dependent chain.
__global__ __launch_bounds__(256) void k_count_gate(
    const int* __restrict__ ei, int* __restrict__ cur,
    float4* __restrict__ zreg, float* __restrict__ gsum,
    const void* __restrict__ edge_attr,
    const void* __restrict__ Wg1, const void* __restrict__ bg1,
    const void* __restrict__ Wg2, const void* __restrict__ bg2,
    const int* __restrict__ flags)
{
    __shared__ float sWg1t[32 * 16];   // transposed: [j][k], row=16 floats -> ds_read_b128
    __shared__ float sBg1[32];
    __shared__ float sWg2[32];
    __shared__ float sBg2;
    const int tid = threadIdx.x;
    const int fl = flags[0];
    const bool f32in = (fl & 1) != 0;
    const bool i64   = (fl & 2) != 0;
    for (int i = tid; i < 32 * 16; i += 256) {
        const int j = i >> 4, k = i & 15;
        sWg1t[i] = ldf(Wg1, k * 32 + j, f32in);
    }
    if (tid < 32) sBg1[tid] = ldf(bg1, tid, f32in);
    if (tid >= 32 && tid < 64) sWg2[tid - 32] = ldf(Wg2, tid - 32, f32in);
    if (tid == 0) sBg2 = ldf(bg2, 0, f32in);

    const int gid = blockIdx.x * 256 + tid;
    for (int i = gid; i < N_NODES * 68 / 4; i += 6250 * 256)   // accum + dsum_g only
        zreg[i] = make_float4(0.f, 0.f, 0.f, 0.f);
    const int tgt = i64 ? ei[2 * (N_EDGES + gid)] : ei[N_EDGES + gid];
    atomicAdd(&cur[tgt], 1);

    __syncthreads();
    float ea[EDGE_DIM];
    load16f(edge_attr, (long)gid * EDGE_DIM, f32in, ea);
    float g = sBg2;
#pragma unroll
    for (int j = 0; j < 32; ++j) {
        float hv = sBg1[j];
        const float4* wr = (const float4*)&sWg1t[j * 16];
#pragma unroll
        for (int k4 = 0; k4 < 4; ++k4) {
            const float4 wv = wr[k4];    // broadcast ds_read_b128
            hv += ea[4*k4]   * wv.x + ea[4*k4+1] * wv.y
                + ea[4*k4+2] * wv.z + ea[4*k4+3] * wv.w;
        }
        hv = hv / (1.f + __expf(-hv));   // SiLU
        g += hv * sWg2[j];
    }
    g = 1.f / (1.f + __expf(-g));        // sigmoid
    atomicAdd(&gsum[tgt], g);
}

// ---------------- pass 2b: hierarchical exclusive scan ----------------
__global__ __launch_bounds__(256) void k_bsum(const int* __restrict__ cur,
                                              int* __restrict__ partial)
{
    const int i = blockIdx.x * 256 + threadIdx.x;
    int v = (i < N_NODES) ? cur[i] : 0;
#pragma unroll
    for (int off = 32; off >= 1; off >>= 1) v += __shfl_xor(v, off, 64);
    __shared__ int ws[4];
    if ((threadIdx.x & 63) == 0) ws[threadIdx.x >> 6] = v;
    __syncthreads();
    if (threadIdx.x == 0) partial[blockIdx.x] = ws[0] + ws[1] + ws[2] + ws[3];
}

__global__ void k_bscan(const int* __restrict__ partial, int* __restrict__ poff,
                        int* __restrict__ base)
{
    __shared__ int sp[NBLK];
    for (int i = threadIdx.x; i < NBLK; i += 64) sp[i] = partial[i];
    __syncthreads();
    if (threadIdx.x == 0) {
        int run = 0;
        for (int i = 0; i < NBLK; ++i) { int t = sp[i]; sp[i] = run; run += t; }
        base[N_NODES] = N_EDGES;
    }
    __syncthreads();
    for (int i = threadIdx.x; i < NBLK; i += 64) poff[i] = sp[i];
}

__global__ __launch_bounds__(256) void k_bfinal(int* __restrict__ cur,
                                                const int* __restrict__ poff,
                                                int* __restrict__ base)
{
    const int i = blockIdx.x * 256 + threadIdx.x;
    const int lane = threadIdx.x & 63;
    const int wave = threadIdx.x >> 6;
    int v = (i < N_NODES) ? cur[i] : 0;
    int s = v;
#pragma unroll
    for (int off = 1; off < 64; off <<= 1) {
        int t = __shfl_up(s, off, 64);
        if (lane >= off) s += t;
    }
    __shared__ int wsum[4];
    if (lane == 63) wsum[wave] = s;
    __syncthreads();
    int wb = 0;
    for (int w = 0; w < wave; ++w) wb += wsum[w];
    if (i < N_NODES) {
        base[i] = poff[blockIdx.x] + wb + s - v;   // exclusive prefix
        cur[i] = 0;                                 // reset for scatter's slot counter
    }
}

// ---------------- pass 2c: pure CSR scatter ----------------
// one thread per edge; packs src:17|tgt:17|eid:21 into u64. Chain is just
// ei load -> base gather + atomic ret -> 8B scatter write; everything else
// was moved out so occupancy + wave count hide the far-atomic latency.
__global__ __launch_bounds__(256) void k_scatter(
    const int* __restrict__ ei, const int* __restrict__ base, int* __restrict__ cur,
    u64* __restrict__ perm8, const int* __restrict__ flags)
{
    const int e = blockIdx.x * 256 + threadIdx.x;          // grid == E exactly
    const bool i64 = (flags[0] & 2) != 0;
    int src, tgt;
    if (i64) { src = ei[2 * e]; tgt = ei[2 * (N_EDGES + e)]; }
    else     { src = ei[e];     tgt = ei[N_EDGES + e]; }
    const int pos = base[tgt] + atomicAdd(&cur[tgt], 1);
    perm8[pos] = (u64)(u32)src | ((u64)(u32)tgt << 17) | ((u64)(u32)e << 34);
}

// ---------------- pass 3: fused attention + segmented aggregation ----------------
// Register-pipelined (round 0 fix): chunk's perm8 entries loaded once into lane
// registers, src/tgt/eid broadcast via readlane (SGPR-resident), and edge jj+1's
// edge_attr/xl/xr gathers issue while edge jj computes (rotating ea buffer).

__device__ __forceinline__ void seg_flush(
    float* __restrict__ accum, float* __restrict__ dsum_g,
    int t, int lane, float acc, float dsum)
{
    atomicAdd(&accum[(size_t)t * 64 + lane], acc);
    if ((lane & 15) == 0) atomicAdd(&dsum_g[t * 4 + (lane >> 4)], dsum);
}

template<bool F32IN>
__device__ __forceinline__ void ea_issue(const void* __restrict__ edge_attr,
                                         int eid, uint4* r)
{
    if constexpr (F32IN) {
        const uint4* q = (const uint4*)edge_attr + (size_t)eid * 4;
        r[0] = q[0]; r[1] = q[1]; r[2] = q[2]; r[3] = q[3];
    } else {
        const uint4* q = (const uint4*)((const u16*)edge_attr + (size_t)eid * 16);
        r[0] = q[0]; r[1] = q[1];
    }
}

template<bool F32IN>
__device__ __forceinline__ void ea_vals(const uint4* r, float* out)
{
    const u32* w = (const u32*)r;
    if constexpr (F32IN) {
#pragma unroll
        for (int i = 0; i < 16; ++i) out[i] = __uint_as_float(w[i]);
    } else {
#pragma unroll
        for (int i = 0; i < 8; ++i) {
            out[2*i]   = __uint_as_float(w[i] << 16);
            out[2*i+1] = __uint_as_float(w[i] & 0xFFFF0000u);
        }
    }
}

// unpack src:17|tgt:17|eid:21 from the two 32-bit halves held in lane JJ
#define PERM_EXTRACT(JJ, S, T, E2) do { \
    const u32 _lo = (u32)__builtin_amdgcn_readlane(plo, (JJ)); \
    const u32 _hi = (u32)__builtin_amdgcn_readlane(phi, (JJ)); \
    (S)  = (int)(_lo & 0x1FFFFu); \
    (T)  = (int)(((_lo >> 17) | (_hi << 15)) & 0x1FFFFu); \
    (E2) = (int)(_hi >> 2); } while (0)

template<bool F32IN>
__device__ __forceinline__ void attn_run(
    const u64* __restrict__ perm8, const void* __restrict__ edge_attr,
    const u16* __restrict__ xl, const u16* __restrict__ xr,
    float* __restrict__ accum, float* __restrict__ dsum_g,
    const float* We_c, float att_c, int lane, int j0)
{
    // whole chunk's perm entries, one coalesced load (lanes 0..CHUNK-1 used)
    const u64 pl = perm8[j0 + (lane & (CHUNK - 1))];
    const int plo = (int)(u32)pl;
    const int phi = (int)(u32)(pl >> 32);

    int s_cur, t_cur, e_cur;
    PERM_EXTRACT(0, s_cur, t_cur, e_cur);

    uint4 ear[F32IN ? 4 : 2];
    ea_issue<F32IN>(edge_attr, e_cur, ear);
    u32 xl_c = xl[(size_t)s_cur * 64 + lane];
    u32 xr_c = xr[(size_t)t_cur * 64 + lane];

    int cur_t = t_cur;
    float acc = 0.f, dsum = 0.f;

#pragma unroll
    for (int jj = 0; jj < CHUNK; ++jj) {
        // consume edge jj's operands (vmcnt wait lands here), collapsing the
        // fat ea registers to one scalar so the buffer can be reissued
        float eav[16];
        ea_vals<F32IN>(ear, eav);
        float ee = 0.f;
#pragma unroll
        for (int k = 0; k < EDGE_DIM; ++k) ee = fmaf(eav[k], We_c[k], ee);
        const float xlf = bf2f((u16)xl_c);
        const float xrf = bf2f((u16)xr_c);

        // issue edge jj+1's gathers into the same (now dead) registers
        int s_nxt = s_cur, t_nxt = t_cur, e_nxt = e_cur;
        u32 xl_n = xl_c, xr_n = xr_c;
        if (jj + 1 < CHUNK) {
            PERM_EXTRACT(jj + 1, s_nxt, t_nxt, e_nxt);
            ea_issue<F32IN>(edge_attr, e_nxt, ear);
            xl_n = xl[(size_t)s_nxt * 64 + lane];
            if (t_nxt != t_cur)                     // wave-uniform (SGPR cmp)
                xr_n = xr[(size_t)t_nxt * 64 + lane];
        }

        // finish edge jj
        if (t_cur != cur_t) {                       // wave-uniform
            seg_flush(accum, dsum_g, cur_t, lane, acc, dsum);
            cur_t = t_cur; acc = 0.f; dsum = 0.f;
        }
        float m = xlf + xrf + ee;
        m = fmaxf(m, m * NEG_SLOPE);                // leaky_relu
        float t = att_c * m;
        DPP_ROR_ADD(t, 1);                          // 16-lane head sum (DPP row)
        DPP_ROR_ADD(t, 2);
        DPP_ROR_ADD(t, 4);
        DPP_ROR_ADD(t, 8);
        // softmax shift skipped: |alpha| small at these scales; normalized by dsum later
        const float a = __expf(t);
        acc  += a * xlf;
        dsum += a;

        s_cur = s_nxt; t_cur = t_nxt; e_cur = e_nxt;
        xl_c = xl_n;   xr_c = xr_n;
    }
    seg_flush(accum, dsum_g, cur_t, lane, acc, dsum);
}

__global__ __launch_bounds__(256, 8) void k_attn_agg(
    const u64* __restrict__ perm8,
    const void* __restrict__ edge_attr,  // [E,16]
    const void* __restrict__ We,         // [16,64]
    const void* __restrict__ att,        // [4,16] flat 64
    const u16* __restrict__ xl, const u16* __restrict__ xr,
    float* __restrict__ accum,           // [N,64]
    float* __restrict__ dsum_g,          // [N,4]
    const int* __restrict__ flags)
{
    const bool f32in = (flags[0] & 1) != 0;
    const int lane = threadIdx.x & 63;
    const int wid = blockIdx.x * 4 + (threadIdx.x >> 6);
    const int j0 = wid * CHUNK;               // E == #waves * CHUNK exactly

    float We_c[EDGE_DIM];
#pragma unroll
    for (int k = 0; k < EDGE_DIM; ++k) We_c[k] = ldf(We, k * 64 + lane, f32in);
    const float att_c = ldf(att, lane, f32in);

    if (f32in) attn_run<true >(perm8, edge_attr, xl, xr, accum, dsum_g, We_c, att_c, lane, j0);
    else       attn_run<false>(perm8, edge_attr, xl, xr, accum, dsum_g, We_c, att_c, lane, j0);
}

// ---------------- pass 4: streaming epilogue ----------------
__global__ __launch_bounds__(256) void k_epilogue(
    const int* __restrict__ base,
    const float* __restrict__ accum, const float* __restrict__ dsum_g,
    const float* __restrict__ gsum,
    const void* __restrict__ conv_bias, const void* __restrict__ gamma,
    const void* __restrict__ beta, const void* __restrict__ x,
    void* __restrict__ out, const int* __restrict__ flags)
{
    const bool f32in = (flags[0] & 1) != 0;
    const int lane = threadIdx.x & 63;
    const int wave = threadIdx.x >> 6;
    const int n = blockIdx.x * 4 + wave;
    if (n >= N_NODES) return;
    const int h = lane >> 4;

    float v = accum[(size_t)n * 64 + lane];
    const float d = dsum_g[n * 4 + h];
    v = (d > 0.f) ? v / d : 0.f;               // deg-0 node -> 0
    v += ldf(conv_bias, lane, f32in);
    const int deg = base[n + 1] - base[n];
    const float mg = gsum[n] / fmaxf((float)deg, 1.0f);
    v *= mg;

    float s = v;
#pragma unroll
    for (int m2 = 32; m2 >= 1; m2 >>= 1) s += __shfl_xor(s, m2, 64);
    const float mu = s * (1.f / 64.f);
    const float diff = v - mu;
    float q = diff * diff;
#pragma unroll
    for (int m2 = 32; m2 >= 1; m2 >>= 1) q += __shfl_xor(q, m2, 64);
    const float var = q * (1.f / 64.f);

    float y = diff * rsqrtf(var + LN_EPS) * ldf(gamma, lane, f32in) + ldf(beta, lane, f32in);
    y = y / (1.f + __expf(-y));                // SiLU
    const float r = y + ldf(x, n * 64 + lane, f32in);
    if (f32in) ((float*)out)[(size_t)n * 64 + lane] = r;
    else       ((u16*)out)[(size_t)n * 64 + lane] = f2bf(r);
}

extern "C" void kernel_launch(void* const* d_in, const int* in_sizes, int n_in,
                              void* d_out, int out_size, void* d_ws, size_t ws_size,
                              hipStream_t stream)
{
    const void* x   = d_in[0];
    const int* ei   = (const int*)d_in[1];
    const void* ea  = d_in[2];
    const void* Wl  = d_in[3];
    const void* bl  = d_in[4];
    const void* Wr  = d_in[5];
    const void* br  = d_in[6];
    const void* We  = d_in[7];
    const void* att = d_in[8];
    const void* cb  = d_in[9];
    const void* Wg1 = d_in[10];
    const void* bg1 = d_in[11];
    const void* Wg2 = d_in[12];
    const void* bg2 = d_in[13];
    const void* gam = d_in[14];
    const void* bet = d_in[15];

    char* ws = (char*)d_ws;
    int*   flags   = (int*)ws;                    // @0, 16 B
    int*   cur     = (int*)(ws + 16);             // N ints
    int*   base    = (int*)(ws + 400016);         // N+1 ints
    int*   partial = (int*)(ws + 800032);         // NBLK ints
    int*   poff    = (int*)(ws + 801600);         // NBLK ints
    u64*   perm8   = (u64*)(ws + 803168);         // E u64 = 12.8 MB
    float* accum   = (float*)(ws + 13603168);     // N*64 f32  } contiguous
    float* dsum_g  = (float*)(ws + 39203168);     // N*4 f32   } zero region (N*68)
    float* gsum    = (float*)(ws + 40803168);     // N f32, zeroed in k_sniff_zero
    u16*   xl      = (u16*)(ws + 41203168);       // N*64 bf16
    u16*   xr      = (u16*)(ws + 54003168);       // N*64 bf16 -> end 66,803,168

    k_sniff_zero<<<197, 256, 0, stream>>>((const u32*)x, ei, flags, (int4*)cur,
                                          (float4*)gsum);

    k_transform<<<(N_NODES + 63) / 64, 256, 0, stream>>>(x, Wl, bl, Wr, br, xl, xr, flags);

    k_count_gate<<<N_EDGES / 256, 256, 0, stream>>>(
        ei, cur, (float4*)accum, gsum, ea, Wg1, bg1, Wg2, bg2, flags);

    k_bsum<<<NBLK, 256, 0, stream>>>(cur, partial);
    k_bscan<<<1, 64, 0, stream>>>(partial, poff, base);
    k_bfinal<<<NBLK, 256, 0, stream>>>(cur, poff, base);

    k_scatter<<<N_EDGES / 256, 256, 0, stream>>>(ei, base, cur, perm8, flags);

    k_attn_agg<<<N_EDGES / CHUNK / 4, 256, 0, stream>>>(
        perm8, ea, We, att, xl, xr, accum, dsum_g, flags);

    k_epilogue<<<(N_NODES + 3) / 4, 256, 0, stream>>>(
        base, accum, dsum_g, gsum, cb, gam, bet, x, d_out, flags);
}

// Round 4
// 468.185 us; speedup vs baseline: 1.2464x; 1.2464x over previous
//
#include <hip/hip_runtime.h>
#include <hip/hip_bf16.h>
#include <hip/hip_fp16.h>
#include <math.h>

#define N_NODES 100000
#define N_EDGES 1600000
#define IN_DIM 64
#define OUT_DIM 64
#define HEADS 4
#define CH 16          // per-head channels
#define EDGE_DIM 16
#define NEG_SLOPE 0.2f
#define LN_EPS 1e-5f
#define NBLK 391       // ceil(N_NODES/256)
#define CHUNK 32       // CSR positions per wave in k_attn_agg
#define NREP 8         // histogram replicas (divides per-line atomic contention)

typedef unsigned short u16;
typedef unsigned int u32;
typedef unsigned long long u64;
typedef __attribute__((ext_vector_type(8))) short bf16x8;
typedef __attribute__((ext_vector_type(4))) float f32x4;

__device__ __forceinline__ float bf2f(u16 v) {
    return __uint_as_float(((u32)v) << 16);
}
__device__ __forceinline__ u16 f2bf(float f) {
    u32 u = __float_as_uint(f);
    u32 r = (u + 0x7FFFu + ((u >> 16) & 1u)) >> 16;   // RNE
    return (u16)r;
}
// load 16 consecutive bf16 (32B, 16B-aligned) -> 16 floats
__device__ __forceinline__ void load16bf(const u16* p, float* out) {
    const uint4* q = (const uint4*)p;
    uint4 a = q[0], b = q[1];
    u32 w[8] = {a.x, a.y, a.z, a.w, b.x, b.y, b.z, b.w};
#pragma unroll
    for (int i = 0; i < 8; ++i) {
        out[2*i]   = __uint_as_float(w[i] << 16);
        out[2*i+1] = __uint_as_float(w[i] & 0xFFFF0000u);
    }
}
__device__ __forceinline__ void load16f(const void* base, long i, bool f32in, float* out) {
    if (f32in) {
        const float4* q = (const float4*)((const float*)base + i);
        float4 v0 = q[0], v1 = q[1], v2 = q[2], v3 = q[3];
        out[0]=v0.x; out[1]=v0.y; out[2]=v0.z; out[3]=v0.w;
        out[4]=v1.x; out[5]=v1.y; out[6]=v1.z; out[7]=v1.w;
        out[8]=v2.x; out[9]=v2.y; out[10]=v2.z; out[11]=v2.w;
        out[12]=v3.x; out[13]=v3.y; out[14]=v3.z; out[15]=v3.w;
    } else {
        load16bf((const u16*)base + i, out);
    }
}
__device__ __forceinline__ float ldf(const void* base, int i, bool f32in) {
    return f32in ? ((const float*)base)[i] : bf2f(((const u16*)base)[i]);
}

// VALU-pipe 16-lane (DPP row) rotate-add reduction step
#define DPP_ROR_ADD(v, N) do { \
    int _d = __builtin_amdgcn_update_dpp(0, __float_as_int(v), 0x120 + (N), 0xF, 0xF, true); \
    (v) += __int_as_float(_d); } while (0)

// ---------------- pass 0: sniff dtypes (block 0) + zero curR & gsum (blocks 1..) ----------------
// bit0: 1 = float tensors stored f32, 0 = bf16; bit1: 1 = edge_index int64
__global__ void k_sniff_zero(const u32* __restrict__ xw, const int* __restrict__ eiw,
                             int* __restrict__ flags, int4* __restrict__ curR4,
                             float4* __restrict__ gsum4) {
    if (blockIdx.x != 0) {
        const int i = (blockIdx.x - 1) * 256 + threadIdx.x;
        if (i < NREP * N_NODES / 4) curR4[i] = make_int4(0, 0, 0, 0);
        else if (i < NREP * N_NODES / 4 + N_NODES / 4)
            gsum4[i - NREP * N_NODES / 4] = make_float4(0.f, 0.f, 0.f, 0.f);
        return;
    }
    __shared__ int s_f32, s_not64;
    const int t = threadIdx.x;
    if (t == 0) { s_f32 = 0; s_not64 = 0; }
    __syncthreads();
    if (t < 64) {
        u32 w = xw[t];
        for (int h = 0; h < 2; ++h) {
            u32 bits = h ? (w & 0xFFFF0000u) : (w << 16);
            float v = __uint_as_float(bits);
            float a = fabsf(v);
            bool sane = (a == 0.0f) || (a >= 1e-30f && a <= 1000.0f);
            if (!sane || v != v) atomicOr(&s_f32, 1);
        }
    } else if (t < 96) {
        if (eiw[2 * (t - 64) + 1] != 0) atomicOr(&s_not64, 1);
    }
    __syncthreads();
    if (t == 0) flags[0] = s_f32 | ((s_not64 ? 0 : 1) << 1);
}

// ---------------- pass 1: MFMA node transform: [xl|xr] = x @ [Wl|Wr] + [bl|br] ----------------
// block = 256 thr = 4 waves; block handles 64 nodes; wave w covers output cols [w*32, w*32+32)
__global__ __launch_bounds__(256) void k_transform(
    const void* __restrict__ x,
    const void* __restrict__ Wl, const void* __restrict__ bl,
    const void* __restrict__ Wr, const void* __restrict__ br,
    u16* __restrict__ xl, u16* __restrict__ xr,
    const int* __restrict__ flags)
{
    const bool f32in = (flags[0] & 1) != 0;
    const int lane = threadIdx.x & 63;
    const int w = threadIdx.x >> 6;
    const int m0 = blockIdx.x * 64;
    const int col = lane & 15;
    const int quad = lane >> 4;

    // B-fragments (grid-invariant): B[k][n] over cat(Wl,Wr); A/B layout: idx k = quad*8+j
    bf16x8 bfrag[2][2];   // [n-tile][k-chunk]
    float bias[2];
#pragma unroll
    for (int nt = 0; nt < 2; ++nt) {
        const int ng = w * 32 + nt * 16 + col;
        const void* W  = (ng < 64) ? Wl : Wr;
        const void* bi = (ng < 64) ? bl : br;
        const int c = ng & 63;
        bias[nt] = ldf(bi, c, f32in);
#pragma unroll
        for (int kf = 0; kf < 2; ++kf)
#pragma unroll
            for (int j = 0; j < 8; ++j) {
                const int k = kf * 32 + quad * 8 + j;
                bfrag[nt][kf][j] = (short)f2bf(ldf(W, k * 64 + c, f32in));
            }
    }

#pragma unroll
    for (int mt = 0; mt < 4; ++mt) {
        const int mrow = m0 + mt * 16 + col;
        const int m = (mrow < N_NODES) ? mrow : (N_NODES - 1);   // clamp: no OOB read
        bf16x8 afrag[2];
#pragma unroll
        for (int kf = 0; kf < 2; ++kf) {
            const int kb = kf * 32 + quad * 8;
            if (f32in) {
                const float* xp = (const float*)x + (size_t)m * 64 + kb;
#pragma unroll
                for (int j = 0; j < 8; ++j) afrag[kf][j] = (short)f2bf(xp[j]);
            } else {
                afrag[kf] = *(const bf16x8*)((const u16*)x + (size_t)m * 64 + kb);
            }
        }
#pragma unroll
        for (int nt = 0; nt < 2; ++nt) {
            f32x4 c = {bias[nt], bias[nt], bias[nt], bias[nt]};
            c = __builtin_amdgcn_mfma_f32_16x16x32_bf16(afrag[0], bfrag[nt][0], c, 0, 0, 0);
            c = __builtin_amdgcn_mfma_f32_16x16x32_bf16(afrag[1], bfrag[nt][1], c, 0, 0, 0);
            const int ng = w * 32 + nt * 16 + col;
            u16* dst = (ng < 64) ? xl : xr;
            const int cc = ng & 63;
#pragma unroll
            for (int r = 0; r < 4; ++r) {
                const int node = m0 + mt * 16 + quad * 4 + r;   // C: row=quad*4+r, col=lane&15
                if (node < N_NODES) dst[(size_t)node * 64 + cc] = f2bf(c[r]);
            }
        }
    }
}

// ---------------- pass 2a: replicated degree histogram + slot assignment + gate MLP ----------------
// grid 6250 x 256 == E exactly; also grid-strides the accum/dsum zeroing.
// Atomic-storm fix: the histogram atomic goes to replica r = blockIdx&7
// (8x fewer same-line RMWs at the coherence point), RETURNS the slot
// (stored per-edge -> scatter needs no atomics), and the gsum atomic storm
// is gone entirely (gate stored per-edge as f16, summed in attn's
// segmented flush ~150K atomics instead of 1.6M).
__global__ __launch_bounds__(256) void k_count_gate(
    const int* __restrict__ ei, int* __restrict__ curR,
    float4* __restrict__ zreg, u16* __restrict__ slotA, u16* __restrict__ gateA,
    const void* __restrict__ edge_attr,
    const void* __restrict__ Wg1, const void* __restrict__ bg1,
    const void* __restrict__ Wg2, const void* __restrict__ bg2,
    const int* __restrict__ flags)
{
    __shared__ float sWg1t[32 * 16];   // transposed: [j][k], row=16 floats -> ds_read_b128
    __shared__ float sBg1[32];
    __shared__ float sWg2[32];
    __shared__ float sBg2;
    const int tid = threadIdx.x;
    const int fl = flags[0];
    const bool f32in = (fl & 1) != 0;
    const bool i64   = (fl & 2) != 0;
    for (int i = tid; i < 32 * 16; i += 256) {
        const int j = i >> 4, k = i & 15;
        sWg1t[i] = ldf(Wg1, k * 32 + j, f32in);
    }
    if (tid < 32) sBg1[tid] = ldf(bg1, tid, f32in);
    if (tid >= 32 && tid < 64) sWg2[tid - 32] = ldf(Wg2, tid - 32, f32in);
    if (tid == 0) sBg2 = ldf(bg2, 0, f32in);
    __syncthreads();      // before the atomic: barrier must not wait on it

    const int gid = blockIdx.x * 256 + tid;
    for (int i = gid; i < N_NODES * 68 / 4; i += 6250 * 256)   // accum + dsum_g
        zreg[i] = make_float4(0.f, 0.f, 0.f, 0.f);
    const int tgt = i64 ? ei[2 * (N_EDGES + gid)] : ei[N_EDGES + gid];
    const int r = blockIdx.x & (NREP - 1);
    const int slot = atomicAdd(&curR[r * N_NODES + tgt], 1);   // returning; covered by MLP below
    slotA[gid] = (u16)slot;

    float ea[EDGE_DIM];
    load16f(edge_attr, (long)gid * EDGE_DIM, f32in, ea);
    float g = sBg2;
#pragma unroll
    for (int j = 0; j < 32; ++j) {
        float hv = sBg1[j];
        const float4* wr = (const float4*)&sWg1t[j * 16];
#pragma unroll
        for (int k4 = 0; k4 < 4; ++k4) {
            const float4 wv = wr[k4];    // broadcast ds_read_b128
            hv += ea[4*k4]   * wv.x + ea[4*k4+1] * wv.y
                + ea[4*k4+2] * wv.z + ea[4*k4+3] * wv.w;
        }
        hv = hv / (1.f + __expf(-hv));   // SiLU
        g += hv * sWg2[j];
    }
    g = 1.f / (1.f + __expf(-g));        // sigmoid (in [0,1]; f16 exact enough, and
    gateA[gid] = __half_as_ushort(__float2half(g));  // LN cancels per-node uniform scale anyway)
}

// ---------------- pass 2b: hierarchical exclusive scan (over summed replicas) ----------------
__global__ __launch_bounds__(256) void k_bsum(const int* __restrict__ curR,
                                              int* __restrict__ partial)
{
    const int i = blockIdx.x * 256 + threadIdx.x;
    int v = 0;
    if (i < N_NODES) {
#pragma unroll
        for (int r = 0; r < NREP; ++r) v += curR[r * N_NODES + i];
    }
#pragma unroll
    for (int off = 32; off >= 1; off >>= 1) v += __shfl_xor(v, off, 64);
    __shared__ int ws[4];
    if ((threadIdx.x & 63) == 0) ws[threadIdx.x >> 6] = v;
    __syncthreads();
    if (threadIdx.x == 0) partial[blockIdx.x] = ws[0] + ws[1] + ws[2] + ws[3];
}

__global__ void k_bscan(const int* __restrict__ partial, int* __restrict__ poff,
                        int* __restrict__ base)
{
    __shared__ int sp[NBLK];
    for (int i = threadIdx.x; i < NBLK; i += 64) sp[i] = partial[i];
    __syncthreads();
    if (threadIdx.x == 0) {
        int run = 0;
        for (int i = 0; i < NBLK; ++i) { int t = sp[i]; sp[i] = run; run += t; }
        base[N_NODES] = N_EDGES;
    }
    __syncthreads();
    for (int i = threadIdx.x; i < NBLK; i += 64) poff[i] = sp[i];
}

// computes base[] and rewrites curR in place with per-(node,replica) start offsets
__global__ __launch_bounds__(256) void k_bfinal(int* __restrict__ curR,
                                                const int* __restrict__ poff,
                                                int* __restrict__ base)
{
    const int i = blockIdx.x * 256 + threadIdx.x;
    const int lane = threadIdx.x & 63;
    const int wave = threadIdx.x >> 6;
    int c[NREP];
    int v = 0;
    if (i < N_NODES) {
#pragma unroll
        for (int r = 0; r < NREP; ++r) { c[r] = curR[r * N_NODES + i]; v += c[r]; }
    }
    int s = v;
#pragma unroll
    for (int off = 1; off < 64; off <<= 1) {
        int t = __shfl_up(s, off, 64);
        if (lane >= off) s += t;
    }
    __shared__ int wsum[4];
    if (lane == 63) wsum[wave] = s;
    __syncthreads();
    int wb = 0;
    for (int w = 0; w < wave; ++w) wb += wsum[w];
    if (i < N_NODES) {
        int run = poff[blockIdx.x] + wb + s - v;   // exclusive prefix
        base[i] = run;
#pragma unroll
        for (int r = 0; r < NREP; ++r) { curR[r * N_NODES + i] = run; run += c[r]; }
    }
}

// ---------------- pass 2c: atomic-free CSR scatter ----------------
// pos = replica-offset gather + precomputed slot; pure gather/scatter chain.
__global__ __launch_bounds__(256) void k_scatter(
    const int* __restrict__ ei, const int* __restrict__ curR,
    const u16* __restrict__ slotA,
    u64* __restrict__ perm8, const int* __restrict__ flags)
{
    const int e = blockIdx.x * 256 + threadIdx.x;          // grid == E exactly
    const bool i64 = (flags[0] & 2) != 0;
    int src, tgt;
    if (i64) { src = ei[2 * e]; tgt = ei[2 * (N_EDGES + e)]; }
    else     { src = ei[e];     tgt = ei[N_EDGES + e]; }
    const int r = blockIdx.x & (NREP - 1);                 // same mapping as k_count_gate
    const int pos = curR[r * N_NODES + tgt] + (int)slotA[e];
    perm8[pos] = (u64)(u32)src | ((u64)(u32)tgt << 17) | ((u64)(u32)e << 34);
}

// ---------------- pass 3: fused attention + segmented aggregation ----------------
// Register-pipelined: chunk's perm8 entries loaded once into lane registers,
// src/tgt/eid broadcast via readlane (SGPR-resident), and edge jj+1's
// edge_attr/xl/xr/gate gathers issue while edge jj computes.

__device__ __forceinline__ void seg_flush(
    float* __restrict__ accum, float* __restrict__ dsum_g, float* __restrict__ gsum,
    int t, int lane, float acc, float dsum, float gs)
{
    atomicAdd(&accum[(size_t)t * 64 + lane], acc);
    if ((lane & 15) == 0) atomicAdd(&dsum_g[t * 4 + (lane >> 4)], dsum);
    if (lane == 1) atomicAdd(&gsum[t], gs);
}

template<bool F32IN>
__device__ __forceinline__ void ea_issue(const void* __restrict__ edge_attr,
                                         int eid, uint4* r)
{
    if constexpr (F32IN) {
        const uint4* q = (const uint4*)edge_attr + (size_t)eid * 4;
        r[0] = q[0]; r[1] = q[1]; r[2] = q[2]; r[3] = q[3];
    } else {
        const uint4* q = (const uint4*)((const u16*)edge_attr + (size_t)eid * 16);
        r[0] = q[0]; r[1] = q[1];
    }
}

template<bool F32IN>
__device__ __forceinline__ void ea_vals(const uint4* r, float* out)
{
    const u32* w = (const u32*)r;
    if constexpr (F32IN) {
#pragma unroll
        for (int i = 0; i < 16; ++i) out[i] = __uint_as_float(w[i]);
    } else {
#pragma unroll
        for (int i = 0; i < 8; ++i) {
            out[2*i]   = __uint_as_float(w[i] << 16);
            out[2*i+1] = __uint_as_float(w[i] & 0xFFFF0000u);
        }
    }
}

// unpack src:17|tgt:17|eid:21 from the two 32-bit halves held in lane JJ
#define PERM_EXTRACT(JJ, S, T, E2) do { \
    const u32 _lo = (u32)__builtin_amdgcn_readlane(plo, (JJ)); \
    const u32 _hi = (u32)__builtin_amdgcn_readlane(phi, (JJ)); \
    (S)  = (int)(_lo & 0x1FFFFu); \
    (T)  = (int)(((_lo >> 17) | (_hi << 15)) & 0x1FFFFu); \
    (E2) = (int)(_hi >> 2); } while (0)

template<bool F32IN>
__device__ __forceinline__ void attn_run(
    const u64* __restrict__ perm8, const void* __restrict__ edge_attr,
    const u16* __restrict__ gateA,
    const u16* __restrict__ xl, const u16* __restrict__ xr,
    float* __restrict__ accum, float* __restrict__ dsum_g, float* __restrict__ gsum,
    const float* We_c, float att_c, int lane, int j0)
{
    // whole chunk's perm entries, one coalesced load (lanes 0..CHUNK-1 used)
    const u64 pl = perm8[j0 + (lane & (CHUNK - 1))];
    const int plo = (int)(u32)pl;
    const int phi = (int)(u32)(pl >> 32);

    int s_cur, t_cur, e_cur;
    PERM_EXTRACT(0, s_cur, t_cur, e_cur);

    uint4 ear[F32IN ? 4 : 2];
    ea_issue<F32IN>(edge_attr, e_cur, ear);
    u32 xl_c = xl[(size_t)s_cur * 64 + lane];
    u32 xr_c = xr[(size_t)t_cur * 64 + lane];
    float g_c = __half2float(__ushort_as_half(gateA[e_cur]));  // wave-uniform

    int cur_t = t_cur;
    float acc = 0.f, dsum = 0.f, gs = 0.f;

#pragma unroll
    for (int jj = 0; jj < CHUNK; ++jj) {
        // consume edge jj's operands (vmcnt wait lands here), collapsing the
        // fat ea registers to one scalar so the buffer can be reissued
        float eav[16];
        ea_vals<F32IN>(ear, eav);
        float ee = 0.f;
#pragma unroll
        for (int k = 0; k < EDGE_DIM; ++k) ee = fmaf(eav[k], We_c[k], ee);
        const float xlf = bf2f((u16)xl_c);
        const float xrf = bf2f((u16)xr_c);

        // issue edge jj+1's gathers into the same (now dead) registers
        int s_nxt = s_cur, t_nxt = t_cur, e_nxt = e_cur;
        u32 xl_n = xl_c, xr_n = xr_c;
        float g_n = g_c;
        if (jj + 1 < CHUNK) {
            PERM_EXTRACT(jj + 1, s_nxt, t_nxt, e_nxt);
            ea_issue<F32IN>(edge_attr, e_nxt, ear);
            xl_n = xl[(size_t)s_nxt * 64 + lane];
            g_n = __half2float(__ushort_as_half(gateA[e_nxt]));
            if (t_nxt != t_cur)                     // wave-uniform (SGPR cmp)
                xr_n = xr[(size_t)t_nxt * 64 + lane];
        }

        // finish edge jj
        if (t_cur != cur_t) {                       // wave-uniform
            seg_flush(accum, dsum_g, gsum, cur_t, lane, acc, dsum, gs);
            cur_t = t_cur; acc = 0.f; dsum = 0.f; gs = 0.f;
        }
        float m = xlf + xrf + ee;
        m = fmaxf(m, m * NEG_SLOPE);                // leaky_relu
        float t = att_c * m;
        DPP_ROR_ADD(t, 1);                          // 16-lane head sum (DPP row)
        DPP_ROR_ADD(t, 2);
        DPP_ROR_ADD(t, 4);
        DPP_ROR_ADD(t, 8);
        // softmax shift skipped: |alpha| small at these scales; normalized by dsum later
        const float a = __expf(t);
        acc  += a * xlf;
        dsum += a;
        gs   += g_c;

        s_cur = s_nxt; t_cur = t_nxt; e_cur = e_nxt;
        xl_c = xl_n;   xr_c = xr_n;   g_c = g_n;
    }
    seg_flush(accum, dsum_g, gsum, cur_t, lane, acc, dsum, gs);
}

__global__ __launch_bounds__(256, 8) void k_attn_agg(
    const u64* __restrict__ perm8,
    const void* __restrict__ edge_attr,  // [E,16]
    const u16* __restrict__ gateA,       // [E] f16
    const void* __restrict__ We,         // [16,64]
    const void* __restrict__ att,        // [4,16] flat 64
    const u16* __restrict__ xl, const u16* __restrict__ xr,
    float* __restrict__ accum,           // [N,64]
    float* __restrict__ dsum_g,          // [N,4]
    float* __restrict__ gsum,            // [N]
    const int* __restrict__ flags)
{
    const bool f32in = (flags[0] & 1) != 0;
    const int lane = threadIdx.x & 63;
    const int wid = blockIdx.x * 4 + (threadIdx.x >> 6);
    const int j0 = wid * CHUNK;               // E == #waves * CHUNK exactly

    float We_c[EDGE_DIM];
#pragma unroll
    for (int k = 0; k < EDGE_DIM; ++k) We_c[k] = ldf(We, k * 64 + lane, f32in);
    const float att_c = ldf(att, lane, f32in);

    if (f32in) attn_run<true >(perm8, edge_attr, gateA, xl, xr, accum, dsum_g, gsum, We_c, att_c, lane, j0);
    else       attn_run<false>(perm8, edge_attr, gateA, xl, xr, accum, dsum_g, gsum, We_c, att_c, lane, j0);
}

// ---------------- pass 4: streaming epilogue ----------------
__global__ __launch_bounds__(256) void k_epilogue(
    const int* __restrict__ base,
    const float* __restrict__ accum, const float* __restrict__ dsum_g,
    const float* __restrict__ gsum,
    const void* __restrict__ conv_bias, const void* __restrict__ gamma,
    const void* __restrict__ beta, const void* __restrict__ x,
    void* __restrict__ out, const int* __restrict__ flags)
{
    const bool f32in = (flags[0] & 1) != 0;
    const int lane = threadIdx.x & 63;
    const int wave = threadIdx.x >> 6;
    const int n = blockIdx.x * 4 + wave;
    if (n >= N_NODES) return;
    const int h = lane >> 4;

    float v = accum[(size_t)n * 64 + lane];
    const float d = dsum_g[n * 4 + h];
    v = (d > 0.f) ? v / d : 0.f;               // deg-0 node -> 0
    v += ldf(conv_bias, lane, f32in);
    const int deg = base[n + 1] - base[n];
    const float mg = gsum[n] / fmaxf((float)deg, 1.0f);
    v *= mg;

    float s = v;
#pragma unroll
    for (int m2 = 32; m2 >= 1; m2 >>= 1) s += __shfl_xor(s, m2, 64);
    const float mu = s * (1.f / 64.f);
    const float diff = v - mu;
    float q = diff * diff;
#pragma unroll
    for (int m2 = 32; m2 >= 1; m2 >>= 1) q += __shfl_xor(q, m2, 64);
    const float var = q * (1.f / 64.f);

    float y = diff * rsqrtf(var + LN_EPS) * ldf(gamma, lane, f32in) + ldf(beta, lane, f32in);
    y = y / (1.f + __expf(-y));                // SiLU
    const float r = y + ldf(x, n * 64 + lane, f32in);
    if (f32in) ((float*)out)[(size_t)n * 64 + lane] = r;
    else       ((u16*)out)[(size_t)n * 64 + lane] = f2bf(r);
}

extern "C" void kernel_launch(void* const* d_in, const int* in_sizes, int n_in,
                              void* d_out, int out_size, void* d_ws, size_t ws_size,
                              hipStream_t stream)
{
    const void* x   = d_in[0];
    const int* ei   = (const int*)d_in[1];
    const void* ea  = d_in[2];
    const void* Wl  = d_in[3];
    const void* bl  = d_in[4];
    const void* Wr  = d_in[5];
    const void* br  = d_in[6];
    const void* We  = d_in[7];
    const void* att = d_in[8];
    const void* cb  = d_in[9];
    const void* Wg1 = d_in[10];
    const void* bg1 = d_in[11];
    const void* Wg2 = d_in[12];
    const void* bg2 = d_in[13];
    const void* gam = d_in[14];
    const void* bet = d_in[15];

    char* ws = (char*)d_ws;
    int*   flags   = (int*)ws;                    // @0, 16 B
    int*   curR    = (int*)(ws + 16);             // NREP*N ints = 3.2 MB (counts -> offsets)
    int*   base    = (int*)(ws + 3200016);        // N+1 ints
    int*   partial = (int*)(ws + 3600032);        // NBLK ints
    int*   poff    = (int*)(ws + 3601600);        // NBLK ints
    u16*   slotA   = (u16*)(ws + 3603168);        // E u16 = 3.2 MB
    u16*   gateA   = (u16*)(ws + 6803168);        // E f16 = 3.2 MB
    u64*   perm8   = (u64*)(ws + 10003168);       // E u64 = 12.8 MB
    float* accum   = (float*)(ws + 22803168);     // N*64 f32  } contiguous
    float* dsum_g  = (float*)(ws + 48403168);     // N*4 f32   } zero region (N*68)
    float* gsum    = (float*)(ws + 50003168);     // N f32, zeroed in k_sniff_zero
    u16*   xl      = (u16*)(ws + 50403168);       // N*64 bf16
    u16*   xr      = (u16*)(ws + 63203168);       // N*64 bf16 -> end 76,003,168

    // zero curR (200000 int4) + gsum (25000 float4): 225000 elems -> 880 blocks + 1
    k_sniff_zero<<<881, 256, 0, stream>>>((const u32*)x, ei, flags, (int4*)curR,
                                          (float4*)gsum);

    k_transform<<<(N_NODES + 63) / 64, 256, 0, stream>>>(x, Wl, bl, Wr, br, xl, xr, flags);

    k_count_gate<<<N_EDGES / 256, 256, 0, stream>>>(
        ei, curR, (float4*)accum, slotA, gateA, ea, Wg1, bg1, Wg2, bg2, flags);

    k_bsum<<<NBLK, 256, 0, stream>>>(curR, partial);
    k_bscan<<<1, 64, 0, stream>>>(partial, poff, base);
    k_bfinal<<<NBLK, 256, 0, stream>>>(curR, poff, base);

    k_scatter<<<N_EDGES / 256, 256, 0, stream>>>(ei, curR, slotA, perm8, flags);

    k_attn_agg<<<N_EDGES / CHUNK / 4, 256, 0, stream>>>(
        perm8, ea, gateA, We, att, xl, xr, accum, dsum_g, gsum, flags);

    k_epilogue<<<(N_NODES + 3) / 4, 256, 0, stream>>>(
        base, accum, dsum_g, gsum, cb, gam, bet, x, d_out, flags);
}